// Round 10
// baseline (138.551 us; speedup 1.0000x reference)
//
#include <hip/hip_runtime.h>
#include <math.h>

// B*S = 8192 tokens, K=8, N_BASIS=32, RANK=8, D_MODEL=256, D_HID=1024
// ws (bytes): wr f32 [0, 1.0M) | h f32 [1.0M, 3.0M) | wrAh/wrAl bf16 frags [3.0M, 4.0M)
//             | bf1h,bf1l,bf2h,bf2l [4.0M, 4.5M) | wfh,wfl [4.5M, 5.5M)   (~5.8 MB total)
// No g round-trip: down-proj fused into stageB.

typedef unsigned short u16;
typedef __attribute__((ext_vector_type(8))) __bf16 bf16x8;
typedef __attribute__((ext_vector_type(4))) float f32x4;
union ABCast { float4 f; bf16x8 v; };
union BFBits { __bf16 b; u16 u; };
union Pack8 { u16 u[8]; float4 f; };

__device__ __forceinline__ float gelu_exact(float v) {
    return 0.5f * v * (1.0f + erff(v * 0.70710678118654752440f));
}
__device__ __forceinline__ u16 f2bf_bits(float f) { BFBits c; c.b = (__bf16)f; return c.u; }
__device__ __forceinline__ float bfbits2f(u16 u) { BFBits c; c.u = u; return (float)c.b; }

// ---------------- K1: routing -> wr f32 + wr A-frags (bf16 h/l) ----------------
// A-frag (16x16x32): lane holds row = l&15 (token), k = 8*(l>>4)+e (n).
__global__ __launch_bounds__(64) void k_route(
    const int* __restrict__ nidx, const float* __restrict__ nw,
    const float* __restrict__ recipes, float* __restrict__ wr_out,
    u16* __restrict__ wrAh, u16* __restrict__ wrAl)
{
    const int t = blockIdx.x * 64 + threadIdx.x;
    float acc[32];
#pragma unroll
    for (int n = 0; n < 32; n++) acc[n] = 0.f;
#pragma unroll
    for (int k = 0; k < 8; k++) {
        const int   id = nidx[t * 8 + k];
        const float wk = nw[t * 8 + k];
        const float4* row = (const float4*)(recipes + id * 32);
        float v[32];
#pragma unroll
        for (int q = 0; q < 8; q++) {
            float4 f = row[q];
            v[q*4+0] = f.x; v[q*4+1] = f.y; v[q*4+2] = f.z; v[q*4+3] = f.w;
        }
        float m = v[0];
#pragma unroll
        for (int n = 1; n < 32; n++) m = fmaxf(m, v[n]);
        float s = 0.f;
#pragma unroll
        for (int n = 0; n < 32; n++) { float e = expf(v[n] - m); v[n] = e; s += e; }
        const float iv = wk / s;
#pragma unroll
        for (int n = 0; n < 32; n++) acc[n] += v[n] * iv;
    }
    float4* o = (float4*)(wr_out + t * 32);
#pragma unroll
    for (int q = 0; q < 8; q++)
        o[q] = make_float4(acc[q*4+0], acc[q*4+1], acc[q*4+2], acc[q*4+3]);

    // frag emission
    const int tg16 = t >> 4, tl = t & 15;
#pragma unroll
    for (int c = 0; c < 4; c++) {
        Pack8 ph, pl;
#pragma unroll
        for (int e = 0; e < 8; e++) {
            const float v = acc[c*8 + e];
            const u16 hb = f2bf_bits(v);
            ph.u[e] = hb;
            pl.u[e] = f2bf_bits(v - bfbits2f(hb));
        }
        const int lane = c * 16 + tl;
        *(float4*)(wrAh + (tg16*64 + lane)*8) = ph.f;
        *(float4*)(wrAl + (tg16*64 + lane)*8) = pl.f;
    }
}

// ---------------- K2: stage A  x[256] -> h[64], 8 tokens/block (unchanged) ----------------
__global__ __launch_bounds__(512) void k_stageA(
    const float* __restrict__ x, const float* __restrict__ wr,
    const float* __restrict__ A1, const float* __restrict__ A2,
    float* __restrict__ h_out)
{
    __shared__ float ca[8 * 1024];
    __shared__ float tl[8 * 1088];
    const int tid = threadIdx.x;
    const int t0  = blockIdx.x * 8;
    {
        const int e2 = tid * 2;
        float2 c[8];
#pragma unroll
        for (int tt = 0; tt < 8; tt++) c[tt] = make_float2(0.f, 0.f);
#pragma unroll 4
        for (int n = 0; n < 32; n++) {
            const float2 a = *(const float2*)(A1 + n * 1024 + e2);
#pragma unroll
            for (int tt = 0; tt < 8; tt++) {
                const float s = wr[(t0 + tt) * 32 + n];
                c[tt].x += s * a.x; c[tt].y += s * a.y;
            }
        }
#pragma unroll
        for (int tt = 0; tt < 8; tt++) *(float2*)(ca + tt * 1024 + e2) = c[tt];
    }
    __syncthreads();
    {
        const int t = tid >> 6, g = tid & 63, j = g >> 2, eh = g & 3;
        float xr[16];
#pragma unroll
        for (int i = 0; i < 16; i++) xr[i] = x[(t0 + t) * 256 + i * 16 + j];
        float tr[16];
#pragma unroll
        for (int q = 0; q < 16; q++) tr[q] = 0.f;
#pragma unroll
        for (int i = 0; i < 16; i++) {
            const float xv = xr[i];
#pragma unroll
            for (int q = 0; q < 4; q++) {
                const float4 cv = *(const float4*)(ca + t * 1024 + i * 64 + eh * 16 + q * 4);
                tr[q*4+0] += xv * cv.x; tr[q*4+1] += xv * cv.y;
                tr[q*4+2] += xv * cv.z; tr[q*4+3] += xv * cv.w;
            }
        }
#pragma unroll
        for (int q = 0; q < 4; q++)
            *(float4*)(tl + t * 1088 + j * 68 + eh * 16 + q * 4) =
                make_float4(tr[q*4+0], tr[q*4+1], tr[q*4+2], tr[q*4+3]);
    }
    __syncthreads();
    {
        const int e2 = tid * 2;
        float2 c[8];
#pragma unroll
        for (int tt = 0; tt < 8; tt++) c[tt] = make_float2(0.f, 0.f);
#pragma unroll 4
        for (int n = 0; n < 32; n++) {
            const float2 a = *(const float2*)(A2 + n * 1024 + e2);
#pragma unroll
            for (int tt = 0; tt < 8; tt++) {
                const float s = wr[(t0 + tt) * 32 + n];
                c[tt].x += s * a.x; c[tt].y += s * a.y;
            }
        }
#pragma unroll
        for (int tt = 0; tt < 8; tt++) *(float2*)(ca + tt * 1024 + e2) = c[tt];
    }
    __syncthreads();
    {
        const int t = tid >> 6, g = tid & 63, k = g >> 3, l = g & 7;
        float acc = 0.f;
#pragma unroll
        for (int j = 0; j < 16; j++) {
#pragma unroll
            for (int r = 0; r < 8; r++) {
                acc += tl[t * 1088 + j * 68 + r * 8 + k] *
                       ca[t * 1024 + r * 128 + j * 8 + l];
            }
        }
        h_out[(t0 + t) * 64 + g] = acc;
    }
}

// ---------------- K3a: basis banks -> bf16 h/l B-frags ----------------
__global__ __launch_bounds__(256) void k_bsplit(
    const float* __restrict__ B1, const float* __restrict__ B2,
    u16* __restrict__ o1h, u16* __restrict__ o1l,
    u16* __restrict__ o2h, u16* __restrict__ o2l)
{
    const int slot = blockIdx.x * 256 + threadIdx.x;   // 0..16383
    const int bank = slot >> 13, r = (slot >> 10) & 7, g = (slot >> 6) & 15, l = slot & 63;
    const int c = l & 15, nb = 8 * (l >> 4);
    const int base = (bank == 0)
        ? ((g >> 1) * 256 + r * 32 + (g & 1) * 16 + c)      // B1[n][i][r][k]
        : (r * 256 + (g >> 1) * 32 + (g & 1) * 16 + c);     // B2[n][r][j][l2]
    const float* S = (bank ? B2 : B1) + base + nb * 2048;
    Pack8 ph, pl;
#pragma unroll
    for (int e = 0; e < 8; e++) {
        const float v = S[e * 2048];
        const u16 hb = f2bf_bits(v);
        ph.u[e] = hb;
        pl.u[e] = f2bf_bits(v - bfbits2f(hb));
    }
    const int d = ((r * 16 + g) * 64 + l) * 8;
    *(float4*)((bank ? o2h : o1h) + d) = ph.f;
    *(float4*)((bank ? o2l : o1l) + d) = pl.f;
}

// ---------------- K3b: W[1024][256] -> bf16 h/l B-frags for down-proj ----------------
__global__ __launch_bounds__(256) void k_wsplit(
    const float* __restrict__ W, u16* __restrict__ wfh, u16* __restrict__ wfl)
{
    const int slot = blockIdx.x * 256 + threadIdx.x;   // 0..32767
    const int ng = slot >> 11, kc = (slot >> 6) & 31, l = slot & 63;
    const float* S = W + (kc * 32 + 8 * (l >> 4)) * 256 + ng * 16 + (l & 15);
    Pack8 ph, pl;
#pragma unroll
    for (int e = 0; e < 8; e++) {
        const float v = S[e * 256];
        const u16 hb = f2bf_bits(v);
        ph.u[e] = hb;
        pl.u[e] = f2bf_bits(v - bfbits2f(hb));
    }
    const int d = ((ng * 32 + kc) * 64 + l) * 8;
    *(float4*)(wfh + d) = ph.f;
    *(float4*)(wfl + d) = pl.f;
}

// ---------------- K4: fused stageB + down-proj, 16 tokens/block, 1024 thr (16 waves) ----
// Round 9 showed wall = LDS + VALU + MFMA fully serialized (2 barriers/r lockstep).
// This round: (1) P2+P3 fused, t2 deleted (per-lane t2q in regs, h via wave-uniform
// scalar loads) -> LDS 25->16 ops/lane/r; (2) cb1/cb2 double-buffered, ONE barrier/r:
// build(r+1) MFMA overlaps fused-P2P3(r) VALU/LDS across drifting waves.
__global__ __launch_bounds__(1024, 2) void k_fusedB(
    const float* __restrict__ hin,
    const u16* __restrict__ wrAh, const u16* __restrict__ wrAl,
    const u16* __restrict__ bf1h, const u16* __restrict__ bf1l,
    const u16* __restrict__ bf2h, const u16* __restrict__ bf2l,
    const u16* __restrict__ wfh, const u16* __restrict__ wfl,
    const float* __restrict__ bias, float* __restrict__ y)
{
    __shared__ __align__(16) unsigned char smem[67584];
    float* cb1 = (float*)smem;          // [2][16][264]  33792 B
    float* cb2 = cb1 + 2 * 16 * 264;    // [2][16][264]  33792 B -> end 67584
    u16* gAh = (u16*)smem;              // [32][64][8]   (phase 2, reuse)
    u16* gAl = gAh + 16384;             // end 65536 B

    const int tid = threadIdx.x;
    const int l   = tid & 63;
    const int w   = tid >> 6;           // 0..15 = token for P2P3
    const int tg  = blockIdx.x;         // 16-token group
    const int t0  = tg * 16;

    // h for this wave's token: wave-uniform address -> scalar loads (64 uniform floats)
    const int wu = __builtin_amdgcn_readfirstlane(w);
    const float* hp = hin + (t0 + wu) * 64;
    float hsg[64];
#pragma unroll
    for (int q = 0; q < 64; q++) hsg[q] = hp[q];

    // wr A-frags (same for all waves)
    ABCast cu;
    cu.f = *(const float4*)(wrAh + (tg * 64 + l) * 8); const bf16x8 wra_h = cu.v;
    cu.f = *(const float4*)(wrAl + (tg * 64 + l) * 8); const bf16x8 wra_l = cu.v;

    // P1 assignment: waves 0-7 -> cb1, 8-15 -> cb2; 2 groups per wave
    const bool isB2 = (w >= 8);
    const u16* bsrc_h = isB2 ? bf2h : bf1h;
    const u16* bsrc_l = isB2 ? bf2l : bf1l;
    float* cdst0 = isB2 ? cb2 : cb1;
    const int g0 = (w & 7) * 2;

    // P2P3 maps
    const int k0 = (l & 7) * 4, l0 = (l >> 3) * 4;

    float o[4][4];
#pragma unroll
    for (int a = 0; a < 4; a++)
#pragma unroll
        for (int li = 0; li < 4; li++) o[a][li] = 0.f;

    float4 pbh0, pbl0, pbh1, pbl1;
#define LOADB(R) {                                                              \
    const int rb_ = (R) * 16;                                                   \
    pbh0 = *(const float4*)(bsrc_h + ((rb_ + g0 + 0)*64 + l)*8);                \
    pbl0 = *(const float4*)(bsrc_l + ((rb_ + g0 + 0)*64 + l)*8);                \
    pbh1 = *(const float4*)(bsrc_h + ((rb_ + g0 + 1)*64 + l)*8);                \
    pbl1 = *(const float4*)(bsrc_l + ((rb_ + g0 + 1)*64 + l)*8); }
#define BUILD(BSEL) {                                                           \
    float* cdst = cdst0 + (BSEL) * 4224;                                        \
    ABCast ch_, cl_;                                                            \
    ch_.f = pbh0; cl_.f = pbl0;                                                 \
    f32x4 cc = {0.f, 0.f, 0.f, 0.f};                                            \
    cc = __builtin_amdgcn_mfma_f32_16x16x32_bf16(wra_h, ch_.v, cc, 0, 0, 0);    \
    cc = __builtin_amdgcn_mfma_f32_16x16x32_bf16(wra_h, cl_.v, cc, 0, 0, 0);    \
    cc = __builtin_amdgcn_mfma_f32_16x16x32_bf16(wra_l, ch_.v, cc, 0, 0, 0);    \
    { const int gg = g0;                                                        \
      float* cd = cdst + (gg >> 1) * 32 + (gg & 1) * 16 + (l & 15);             \
      _Pragma("unroll")                                                         \
      for (int reg = 0; reg < 4; reg++) cd[(4 * (l >> 4) + reg) * 264] = cc[reg]; } \
    ch_.f = pbh1; cl_.f = pbl1;                                                 \
    f32x4 cc2 = {0.f, 0.f, 0.f, 0.f};                                           \
    cc2 = __builtin_amdgcn_mfma_f32_16x16x32_bf16(wra_h, ch_.v, cc2, 0, 0, 0);  \
    cc2 = __builtin_amdgcn_mfma_f32_16x16x32_bf16(wra_h, cl_.v, cc2, 0, 0, 0);  \
    cc2 = __builtin_amdgcn_mfma_f32_16x16x32_bf16(wra_l, ch_.v, cc2, 0, 0, 0);  \
    { const int gg = g0 + 1;                                                    \
      float* cd = cdst + (gg >> 1) * 32 + (gg & 1) * 16 + (l & 15);             \
      _Pragma("unroll")                                                         \
      for (int reg = 0; reg < 4; reg++) cd[(4 * (l >> 4) + reg) * 264] = cc2[reg]; } }

    // prologue: build r=0 into buf0; prefetch r=1
    LOADB(0);
    BUILD(0);
    LOADB(1);
    __syncthreads();

#pragma unroll 1
    for (int r = 0; r < 8; r++) {
        // ---- build r+1 into buf[(r+1)&1] (MFMA; overlaps P2P3 below across waves) ----
        if (r < 7) {
            BUILD((r + 1) & 1);
            if (r < 6) LOADB(r + 2);   // lands during P2P3
        }

        // ---- fused P2P3 from buf[r&1] (no t2; h from scalar regs) ----
        {
            const float* c1b = cb1 + (r & 1) * 4224 + w * 264;
            const float* c2b = cb2 + (r & 1) * 4224 + w * 264;
            float t2q[8][4];
#pragma unroll
            for (int j = 0; j < 8; j++)
#pragma unroll
                for (int a = 0; a < 4; a++) t2q[j][a] = 0.f;
#pragma unroll
            for (int i = 0; i < 8; i++) {
                const float4 c1 = *(const float4*)(c1b + i * 32 + k0);
                const float cv[4] = {c1.x, c1.y, c1.z, c1.w};
#pragma unroll
                for (int j = 0; j < 8; j++) {
                    const float hv = hsg[i * 8 + j];
#pragma unroll
                    for (int a = 0; a < 4; a++) t2q[j][a] += hv * cv[a];
                }
            }
#pragma unroll
            for (int j = 0; j < 8; j++) {
                const float4 c2 = *(const float4*)(c2b + j * 32 + l0);
                const float cv[4] = {c2.x, c2.y, c2.z, c2.w};
#pragma unroll
                for (int a = 0; a < 4; a++)
#pragma unroll
                    for (int li = 0; li < 4; li++)
                        o[a][li] += t2q[j][a] * cv[li];
            }
        }
        __syncthreads();   // single barrier per r (writes hit buf read at r-1)
    }
#undef LOADB
#undef BUILD

    // ---- epilogue: gelu + split -> gA frags (LDS reuse; all reads done at last barrier) ----
    {
        const int lane2 = (l0 >> 3) * 16 + w;
        const int e0 = l0 & 7;
#pragma unroll
        for (int a = 0; a < 4; a++) {
            u16 hv[4], lv[4];
#pragma unroll
            for (int li = 0; li < 4; li++) {
                const float v = gelu_exact(o[a][li]);
                const u16 hb = f2bf_bits(v);
                hv[li] = hb;
                lv[li] = f2bf_bits(v - bfbits2f(hb));
            }
            const int step = k0 + a;
            *(ushort4*)(gAh + (step * 64 + lane2) * 8 + e0) = make_ushort4(hv[0], hv[1], hv[2], hv[3]);
            *(ushort4*)(gAl + (step * 64 + lane2) * 8 + e0) = make_ushort4(lv[0], lv[1], lv[2], lv[3]);
        }
    }
    __syncthreads();

    // ---- down-proj: y[16][256] = g @ W + b ; waves 0-7, wave w owns n-groups {w, w+8} ----
    if (w < 8) {
        f32x4 dacc0 = {0.f, 0.f, 0.f, 0.f}, dacc1 = {0.f, 0.f, 0.f, 0.f};
        const int wb0 = w * 16384 + l * 8;         // (ng*32+kc)*512 + l*8
        const int wb1 = (w + 8) * 16384 + l * 8;
#pragma unroll 2
        for (int kc = 0; kc < 32; kc++) {
            cu.f = *(const float4*)(gAh + (kc * 64 + l) * 8); const bf16x8 ah = cu.v;
            cu.f = *(const float4*)(gAl + (kc * 64 + l) * 8); const bf16x8 al = cu.v;
            ABCast c0, c1, c2, c3;
            c0.f = *(const float4*)(wfh + wb0 + kc * 512); const bf16x8 bh0 = c0.v;
            c1.f = *(const float4*)(wfl + wb0 + kc * 512); const bf16x8 bl0 = c1.v;
            c2.f = *(const float4*)(wfh + wb1 + kc * 512); const bf16x8 bh1 = c2.v;
            c3.f = *(const float4*)(wfl + wb1 + kc * 512); const bf16x8 bl1 = c3.v;
            dacc0 = __builtin_amdgcn_mfma_f32_16x16x32_bf16(ah, bh0, dacc0, 0, 0, 0);
            dacc0 = __builtin_amdgcn_mfma_f32_16x16x32_bf16(ah, bl0, dacc0, 0, 0, 0);
            dacc0 = __builtin_amdgcn_mfma_f32_16x16x32_bf16(al, bh0, dacc0, 0, 0, 0);
            dacc1 = __builtin_amdgcn_mfma_f32_16x16x32_bf16(ah, bh1, dacc1, 0, 0, 0);
            dacc1 = __builtin_amdgcn_mfma_f32_16x16x32_bf16(ah, bl1, dacc1, 0, 0, 0);
            dacc1 = __builtin_amdgcn_mfma_f32_16x16x32_bf16(al, bh1, dacc1, 0, 0, 0);
        }
        // C-frag: col = l&15 (n within group), rows = tokens 4*(l>>4)+reg
        const int n0 = w * 16 + (l & 15);
        const int n1 = (w + 8) * 16 + (l & 15);
        const float b0 = bias[n0], b1 = bias[n1];
        const int tb = t0 + 4 * (l >> 4);
#pragma unroll
        for (int reg = 0; reg < 4; reg++) {
            y[(tb + reg) * 256 + n0] = dacc0[reg] + b0;
            y[(tb + reg) * 256 + n1] = dacc1[reg] + b1;
        }
    }
}

extern "C" void kernel_launch(void* const* d_in, const int* in_sizes, int n_in,
                              void* d_out, int out_size, void* d_ws, size_t ws_size,
                              hipStream_t stream)
{
    const float* x    = (const float*)d_in[0];
    const int*   nidx = (const int*)  d_in[1];
    const float* nw   = (const float*)d_in[2];
    const float* rec  = (const float*)d_in[3];
    const float* A1   = (const float*)d_in[4];
    const float* A2   = (const float*)d_in[5];
    const float* B1   = (const float*)d_in[6];
    const float* B2   = (const float*)d_in[7];
    const float* Wd   = (const float*)d_in[8];
    const float* bd   = (const float*)d_in[9];
    float* y  = (float*)d_out;

    float* wr  = (float*)d_ws;                   // 8192*32 f32
    float* h   = wr + 8192 * 32;                 // 8192*64 f32
    u16* wrAh  = (u16*)(h + 8192 * 64);          // 262144 u16
    u16* wrAl  = wrAh + 262144;
    u16* b1h   = wrAl + 262144;                  // 65536 u16 each
    u16* b1l   = b1h + 65536;
    u16* b2h   = b1l + 65536;
    u16* b2l   = b2h + 65536;
    u16* wfh   = b2l + 65536;                    // 262144 u16 each
    u16* wfl   = wfh + 262144;

    k_route <<<128,  64,   0, stream>>>(nidx, nw, rec, wr, wrAh, wrAl);
    k_stageA<<<1024, 512,  0, stream>>>(x, wr, A1, A2, h);
    k_bsplit<<<64,   256,  0, stream>>>(B1, B2, b1h, b1l, b2h, b2l);
    k_wsplit<<<128,  256,  0, stream>>>(Wd, wfh, wfl);
    k_fusedB<<<512,  1024, 0, stream>>>(h, wrAh, wrAl, b1h, b1l, b2h, b2l, wfh, wfl, bd, y);
}

// Round 11
// 99.095 us; speedup vs baseline: 1.3982x; 1.3982x over previous
//
#include <hip/hip_runtime.h>
#include <math.h>

// B*S = 8192 tokens, K=8, N_BASIS=32, RANK=8, D_MODEL=256, D_HID=1024
// ws (bytes): wr f32 [0, 1.0M) | h f32 [1.0M, 3.0M) | wrAh/wrAl bf16 frags [3.0M, 4.0M)
//             | bf1h,bf1l,bf2h,bf2l [4.0M, 4.5M) | wfh,wfl [4.5M, 5.5M)   (~5.8 MB total)
// No g round-trip: down-proj fused into stageB.

typedef unsigned short u16;
typedef __attribute__((ext_vector_type(8))) __bf16 bf16x8;
typedef __attribute__((ext_vector_type(4))) float f32x4;
union ABCast { float4 f; bf16x8 v; };
union BFBits { __bf16 b; u16 u; };
union Pack8 { u16 u[8]; float4 f; };

__device__ __forceinline__ float gelu_exact(float v) {
    return 0.5f * v * (1.0f + erff(v * 0.70710678118654752440f));
}
__device__ __forceinline__ u16 f2bf_bits(float f) { BFBits c; c.b = (__bf16)f; return c.u; }
__device__ __forceinline__ float bfbits2f(u16 u) { BFBits c; c.u = u; return (float)c.b; }

// ---------------- K1: routing -> wr f32 + wr A-frags (bf16 h/l) ----------------
// A-frag (16x16x32): lane holds row = l&15 (token), k = 8*(l>>4)+e (n).
__global__ __launch_bounds__(64) void k_route(
    const int* __restrict__ nidx, const float* __restrict__ nw,
    const float* __restrict__ recipes, float* __restrict__ wr_out,
    u16* __restrict__ wrAh, u16* __restrict__ wrAl)
{
    const int t = blockIdx.x * 64 + threadIdx.x;
    float acc[32];
#pragma unroll
    for (int n = 0; n < 32; n++) acc[n] = 0.f;
#pragma unroll
    for (int k = 0; k < 8; k++) {
        const int   id = nidx[t * 8 + k];
        const float wk = nw[t * 8 + k];
        const float4* row = (const float4*)(recipes + id * 32);
        float v[32];
#pragma unroll
        for (int q = 0; q < 8; q++) {
            float4 f = row[q];
            v[q*4+0] = f.x; v[q*4+1] = f.y; v[q*4+2] = f.z; v[q*4+3] = f.w;
        }
        float m = v[0];
#pragma unroll
        for (int n = 1; n < 32; n++) m = fmaxf(m, v[n]);
        float s = 0.f;
#pragma unroll
        for (int n = 0; n < 32; n++) { float e = expf(v[n] - m); v[n] = e; s += e; }
        const float iv = wk / s;
#pragma unroll
        for (int n = 0; n < 32; n++) acc[n] += v[n] * iv;
    }
    float4* o = (float4*)(wr_out + t * 32);
#pragma unroll
    for (int q = 0; q < 8; q++)
        o[q] = make_float4(acc[q*4+0], acc[q*4+1], acc[q*4+2], acc[q*4+3]);

    // frag emission
    const int tg16 = t >> 4, tl = t & 15;
#pragma unroll
    for (int c = 0; c < 4; c++) {
        Pack8 ph, pl;
#pragma unroll
        for (int e = 0; e < 8; e++) {
            const float v = acc[c*8 + e];
            const u16 hb = f2bf_bits(v);
            ph.u[e] = hb;
            pl.u[e] = f2bf_bits(v - bfbits2f(hb));
        }
        const int lane = c * 16 + tl;
        *(float4*)(wrAh + (tg16*64 + lane)*8) = ph.f;
        *(float4*)(wrAl + (tg16*64 + lane)*8) = pl.f;
    }
}

// ---------------- K2: stage A  x[256] -> h[64], 8 tokens/block (unchanged) ----------------
__global__ __launch_bounds__(512) void k_stageA(
    const float* __restrict__ x, const float* __restrict__ wr,
    const float* __restrict__ A1, const float* __restrict__ A2,
    float* __restrict__ h_out)
{
    __shared__ float ca[8 * 1024];
    __shared__ float tl[8 * 1088];
    const int tid = threadIdx.x;
    const int t0  = blockIdx.x * 8;
    {
        const int e2 = tid * 2;
        float2 c[8];
#pragma unroll
        for (int tt = 0; tt < 8; tt++) c[tt] = make_float2(0.f, 0.f);
#pragma unroll 4
        for (int n = 0; n < 32; n++) {
            const float2 a = *(const float2*)(A1 + n * 1024 + e2);
#pragma unroll
            for (int tt = 0; tt < 8; tt++) {
                const float s = wr[(t0 + tt) * 32 + n];
                c[tt].x += s * a.x; c[tt].y += s * a.y;
            }
        }
#pragma unroll
        for (int tt = 0; tt < 8; tt++) *(float2*)(ca + tt * 1024 + e2) = c[tt];
    }
    __syncthreads();
    {
        const int t = tid >> 6, g = tid & 63, j = g >> 2, eh = g & 3;
        float xr[16];
#pragma unroll
        for (int i = 0; i < 16; i++) xr[i] = x[(t0 + t) * 256 + i * 16 + j];
        float tr[16];
#pragma unroll
        for (int q = 0; q < 16; q++) tr[q] = 0.f;
#pragma unroll
        for (int i = 0; i < 16; i++) {
            const float xv = xr[i];
#pragma unroll
            for (int q = 0; q < 4; q++) {
                const float4 cv = *(const float4*)(ca + t * 1024 + i * 64 + eh * 16 + q * 4);
                tr[q*4+0] += xv * cv.x; tr[q*4+1] += xv * cv.y;
                tr[q*4+2] += xv * cv.z; tr[q*4+3] += xv * cv.w;
            }
        }
#pragma unroll
        for (int q = 0; q < 4; q++)
            *(float4*)(tl + t * 1088 + j * 68 + eh * 16 + q * 4) =
                make_float4(tr[q*4+0], tr[q*4+1], tr[q*4+2], tr[q*4+3]);
    }
    __syncthreads();
    {
        const int e2 = tid * 2;
        float2 c[8];
#pragma unroll
        for (int tt = 0; tt < 8; tt++) c[tt] = make_float2(0.f, 0.f);
#pragma unroll 4
        for (int n = 0; n < 32; n++) {
            const float2 a = *(const float2*)(A2 + n * 1024 + e2);
#pragma unroll
            for (int tt = 0; tt < 8; tt++) {
                const float s = wr[(t0 + tt) * 32 + n];
                c[tt].x += s * a.x; c[tt].y += s * a.y;
            }
        }
#pragma unroll
        for (int tt = 0; tt < 8; tt++) *(float2*)(ca + tt * 1024 + e2) = c[tt];
    }
    __syncthreads();
    {
        const int t = tid >> 6, g = tid & 63, k = g >> 3, l = g & 7;
        float acc = 0.f;
#pragma unroll
        for (int j = 0; j < 16; j++) {
#pragma unroll
            for (int r = 0; r < 8; r++) {
                acc += tl[t * 1088 + j * 68 + r * 8 + k] *
                       ca[t * 1024 + r * 128 + j * 8 + l];
            }
        }
        h_out[(t0 + t) * 64 + g] = acc;
    }
}

// ---------------- K3a: basis banks -> bf16 h/l B-frags ----------------
__global__ __launch_bounds__(256) void k_bsplit(
    const float* __restrict__ B1, const float* __restrict__ B2,
    u16* __restrict__ o1h, u16* __restrict__ o1l,
    u16* __restrict__ o2h, u16* __restrict__ o2l)
{
    const int slot = blockIdx.x * 256 + threadIdx.x;   // 0..16383
    const int bank = slot >> 13, r = (slot >> 10) & 7, g = (slot >> 6) & 15, l = slot & 63;
    const int c = l & 15, nb = 8 * (l >> 4);
    const int base = (bank == 0)
        ? ((g >> 1) * 256 + r * 32 + (g & 1) * 16 + c)      // B1[n][i][r][k]
        : (r * 256 + (g >> 1) * 32 + (g & 1) * 16 + c);     // B2[n][r][j][l2]
    const float* S = (bank ? B2 : B1) + base + nb * 2048;
    Pack8 ph, pl;
#pragma unroll
    for (int e = 0; e < 8; e++) {
        const float v = S[e * 2048];
        const u16 hb = f2bf_bits(v);
        ph.u[e] = hb;
        pl.u[e] = f2bf_bits(v - bfbits2f(hb));
    }
    const int d = ((r * 16 + g) * 64 + l) * 8;
    *(float4*)((bank ? o2h : o1h) + d) = ph.f;
    *(float4*)((bank ? o2l : o1l) + d) = pl.f;
}

// ---------------- K3b: W[1024][256] -> bf16 h/l B-frags for down-proj ----------------
__global__ __launch_bounds__(256) void k_wsplit(
    const float* __restrict__ W, u16* __restrict__ wfh, u16* __restrict__ wfl)
{
    const int slot = blockIdx.x * 256 + threadIdx.x;   // 0..32767
    const int ng = slot >> 11, kc = (slot >> 6) & 31, l = slot & 63;
    const float* S = W + (kc * 32 + 8 * (l >> 4)) * 256 + ng * 16 + (l & 15);
    Pack8 ph, pl;
#pragma unroll
    for (int e = 0; e < 8; e++) {
        const float v = S[e * 256];
        const u16 hb = f2bf_bits(v);
        ph.u[e] = hb;
        pl.u[e] = f2bf_bits(v - bfbits2f(hb));
    }
    const int d = ((ng * 32 + kc) * 64 + l) * 8;
    *(float4*)(wfh + d) = ph.f;
    *(float4*)(wfl + d) = pl.f;
}

// ---------------- K4: fused stageB + down-proj, 16 tokens/block, 1024 thr (16 waves) ----
// Round-8 structure (70us champion: hreg hoist, prefetch, P2/P3 split) + isolated changes:
//  (a) cb1/cb2 double-buffered, ONE barrier per r: BUILD(r+1)->buf^1 (MFMA) overlaps
//      P2/P3(r)<-buf (VALU/LDS) across drifting waves; parity proven correct in r10 run.
//  (b) s_setprio(1) around BUILD MFMAs (T5; role diversity exists in the drift window).
//  (c) strides 264->256 (reads are single-token per wave -> conflict-free; P1 stores
//      pick up minor 4-way). LDS = 65536(cb dbuf) + 16384(t2) = 81920 -> 2 blocks/CU.
// DO NOT fuse P2+P3 (r10: +2.4x VALU) or hold h[64]/thread (r10: VGPR spill).
__global__ __launch_bounds__(1024, 2) void k_fusedB(
    const float* __restrict__ hin,
    const u16* __restrict__ wrAh, const u16* __restrict__ wrAl,
    const u16* __restrict__ bf1h, const u16* __restrict__ bf1l,
    const u16* __restrict__ bf2h, const u16* __restrict__ bf2l,
    const u16* __restrict__ wfh, const u16* __restrict__ wfl,
    const float* __restrict__ bias, float* __restrict__ y)
{
    __shared__ __align__(16) unsigned char smem[81920];
    float* cb1 = (float*)smem;          // [2][16][256]  32768 B
    float* cb2 = cb1 + 2 * 16 * 256;    // [2][16][256]  32768 B
    float* t2  = cb2 + 2 * 16 * 256;    // [16][256]     16384 B -> end 81920
    u16* gAh = (u16*)smem;              // [32][64][8]   (phase 2, reuse)
    u16* gAl = gAh + 16384;             // end 65536 B

    const int tid = threadIdx.x;
    const int l   = tid & 63;
    const int w   = tid >> 6;           // 0..15 = token for P2/P3
    const int tg  = blockIdx.x;         // 16-token group
    const int t0  = tg * 16;

    // P2/P3 maps
    const int j2 = l >> 3, k42 = l & 7;
    const int k0 = (l & 7) * 4, l0 = (l >> 3) * 4;

    // h values for this wave's token (r-invariant): 8 global b32, 8-lane broadcast, L2-hit
    float hreg[8];
#pragma unroll
    for (int i = 0; i < 8; i++) hreg[i] = hin[(t0 + w) * 64 + i * 8 + j2];

    // wr A-frags (same for all waves)
    ABCast cu;
    cu.f = *(const float4*)(wrAh + (tg * 64 + l) * 8); const bf16x8 wra_h = cu.v;
    cu.f = *(const float4*)(wrAl + (tg * 64 + l) * 8); const bf16x8 wra_l = cu.v;

    // P1 assignment: waves 0-7 -> cb1, 8-15 -> cb2; 2 groups per wave
    const bool isB2 = (w >= 8);
    const u16* bsrc_h = isB2 ? bf2h : bf1h;
    const u16* bsrc_l = isB2 ? bf2l : bf1l;
    float* cdst0 = isB2 ? cb2 : cb1;
    const int g0 = (w & 7) * 2;

    float o[4][4];
#pragma unroll
    for (int a = 0; a < 4; a++)
#pragma unroll
        for (int li = 0; li < 4; li++) o[a][li] = 0.f;

    float4 pbh0, pbl0, pbh1, pbl1;
#define LOADB(R) {                                                              \
    const int rb_ = (R) * 16;                                                   \
    pbh0 = *(const float4*)(bsrc_h + ((rb_ + g0 + 0)*64 + l)*8);                \
    pbl0 = *(const float4*)(bsrc_l + ((rb_ + g0 + 0)*64 + l)*8);                \
    pbh1 = *(const float4*)(bsrc_h + ((rb_ + g0 + 1)*64 + l)*8);                \
    pbl1 = *(const float4*)(bsrc_l + ((rb_ + g0 + 1)*64 + l)*8); }
#define BUILD(BSEL) {                                                           \
    float* cdst = cdst0 + (BSEL) * 4096;                                        \
    __builtin_amdgcn_s_setprio(1);                                              \
    ABCast ch_, cl_;                                                            \
    ch_.f = pbh0; cl_.f = pbl0;                                                 \
    f32x4 cc = {0.f, 0.f, 0.f, 0.f};                                            \
    cc = __builtin_amdgcn_mfma_f32_16x16x32_bf16(wra_h, ch_.v, cc, 0, 0, 0);    \
    cc = __builtin_amdgcn_mfma_f32_16x16x32_bf16(wra_h, cl_.v, cc, 0, 0, 0);    \
    cc = __builtin_amdgcn_mfma_f32_16x16x32_bf16(wra_l, ch_.v, cc, 0, 0, 0);    \
    ch_.f = pbh1; cl_.f = pbl1;                                                 \
    f32x4 cc2 = {0.f, 0.f, 0.f, 0.f};                                           \
    cc2 = __builtin_amdgcn_mfma_f32_16x16x32_bf16(wra_h, ch_.v, cc2, 0, 0, 0);  \
    cc2 = __builtin_amdgcn_mfma_f32_16x16x32_bf16(wra_h, cl_.v, cc2, 0, 0, 0);  \
    cc2 = __builtin_amdgcn_mfma_f32_16x16x32_bf16(wra_l, ch_.v, cc2, 0, 0, 0);  \
    __builtin_amdgcn_s_setprio(0);                                              \
    { const int gg = g0;                                                        \
      float* cd = cdst + (gg >> 1) * 32 + (gg & 1) * 16 + (l & 15);             \
      _Pragma("unroll")                                                         \
      for (int reg = 0; reg < 4; reg++) cd[(4 * (l >> 4) + reg) * 256] = cc[reg]; } \
    { const int gg = g0 + 1;                                                    \
      float* cd = cdst + (gg >> 1) * 32 + (gg & 1) * 16 + (l & 15);             \
      _Pragma("unroll")                                                         \
      for (int reg = 0; reg < 4; reg++) cd[(4 * (l >> 4) + reg) * 256] = cc2[reg]; } }

    // prologue: build r=0 into buf0; prefetch r=1
    LOADB(0);
    BUILD(0);
    LOADB(1);
    __syncthreads();

#pragma unroll 1
    for (int r = 0; r < 8; r++) {
        // ---- build r+1 into buf[(r+1)&1] (MFMA; overlaps P2/P3 below across waves) ----
        if (r < 7) {
            BUILD((r + 1) & 1);
            if (r < 6) LOADB(r + 2);   // lands during P2/P3
        }

        // ---- P2: t2[w][j2*32+k] = sum_i hreg[i] * cb1[buf][w][i*32+k]  (wave-private) ----
        {
            const float* c1b = cb1 + (r & 1) * 4096 + w * 256;
            float4 acc = make_float4(0.f, 0.f, 0.f, 0.f);
#pragma unroll
            for (int i = 0; i < 8; i++) {
                const float  hv = hreg[i];
                const float4 cv = *(const float4*)(c1b + i * 32 + k42 * 4);
                acc.x += hv * cv.x; acc.y += hv * cv.y;
                acc.z += hv * cv.z; acc.w += hv * cv.w;
            }
            *(float4*)(t2 + w * 256 + j2 * 32 + k42 * 4) = acc;
        }
        // no barrier: t2 written and read only by this wave

        // ---- P3: o[a][li] += sum_j t2[w][j*32+k0+a] * cb2[buf][w][j*32+l0+li] ----
        {
            const float* c2b = cb2 + (r & 1) * 4096 + w * 256;
#pragma unroll
            for (int j = 0; j < 8; j++) {
                const float4 tv4 = *(const float4*)(t2 + w * 256 + j * 32 + k0);
                const float4 cv4 = *(const float4*)(c2b + j * 32 + l0);
                const float tv[4] = {tv4.x, tv4.y, tv4.z, tv4.w};
                const float cv[4] = {cv4.x, cv4.y, cv4.z, cv4.w};
#pragma unroll
                for (int a = 0; a < 4; a++)
#pragma unroll
                    for (int li = 0; li < 4; li++)
                        o[a][li] += tv[a] * cv[li];
            }
        }
        __syncthreads();   // single barrier per r (iter r writes buf^1, last read at r-1)
    }
#undef LOADB
#undef BUILD

    // ---- epilogue: gelu + split -> gA frags (LDS reuse; all reads done at last barrier) ----
    {
        const int lane2 = (l0 >> 3) * 16 + w;
        const int e0 = l0 & 7;
#pragma unroll
        for (int a = 0; a < 4; a++) {
            u16 hv[4], lv[4];
#pragma unroll
            for (int li = 0; li < 4; li++) {
                const float v = gelu_exact(o[a][li]);
                const u16 hb = f2bf_bits(v);
                hv[li] = hb;
                lv[li] = f2bf_bits(v - bfbits2f(hb));
            }
            const int step = k0 + a;
            *(ushort4*)(gAh + (step * 64 + lane2) * 8 + e0) = make_ushort4(hv[0], hv[1], hv[2], hv[3]);
            *(ushort4*)(gAl + (step * 64 + lane2) * 8 + e0) = make_ushort4(lv[0], lv[1], lv[2], lv[3]);
        }
    }
    __syncthreads();

    // ---- down-proj: y[16][256] = g @ W + b ; waves 0-7, wave w owns n-groups {w, w+8}
    //      (single gA read serves both -> gA LDS traffic halved) ----
    if (w < 8) {
        f32x4 dacc0 = {0.f, 0.f, 0.f, 0.f}, dacc1 = {0.f, 0.f, 0.f, 0.f};
        const int wb0 = w * 16384 + l * 8;         // (ng*32+kc)*512 + l*8
        const int wb1 = (w + 8) * 16384 + l * 8;
#pragma unroll 2
        for (int kc = 0; kc < 32; kc++) {
            cu.f = *(const float4*)(gAh + (kc * 64 + l) * 8); const bf16x8 ah = cu.v;
            cu.f = *(const float4*)(gAl + (kc * 64 + l) * 8); const bf16x8 al = cu.v;
            ABCast c0, c1, c2, c3;
            c0.f = *(const float4*)(wfh + wb0 + kc * 512); const bf16x8 bh0 = c0.v;
            c1.f = *(const float4*)(wfl + wb0 + kc * 512); const bf16x8 bl0 = c1.v;
            c2.f = *(const float4*)(wfh + wb1 + kc * 512); const bf16x8 bh1 = c2.v;
            c3.f = *(const float4*)(wfl + wb1 + kc * 512); const bf16x8 bl1 = c3.v;
            dacc0 = __builtin_amdgcn_mfma_f32_16x16x32_bf16(ah, bh0, dacc0, 0, 0, 0);
            dacc0 = __builtin_amdgcn_mfma_f32_16x16x32_bf16(ah, bl0, dacc0, 0, 0, 0);
            dacc0 = __builtin_amdgcn_mfma_f32_16x16x32_bf16(al, bh0, dacc0, 0, 0, 0);
            dacc1 = __builtin_amdgcn_mfma_f32_16x16x32_bf16(ah, bh1, dacc1, 0, 0, 0);
            dacc1 = __builtin_amdgcn_mfma_f32_16x16x32_bf16(ah, bl1, dacc1, 0, 0, 0);
            dacc1 = __builtin_amdgcn_mfma_f32_16x16x32_bf16(al, bh1, dacc1, 0, 0, 0);
        }
        // C-frag: col = l&15 (n within group), rows = tokens 4*(l>>4)+reg
        const int n0 = w * 16 + (l & 15);
        const int n1 = (w + 8) * 16 + (l & 15);
        const float b0 = bias[n0], b1 = bias[n1];
        const int tb = t0 + 4 * (l >> 4);
#pragma unroll
        for (int reg = 0; reg < 4; reg++) {
            y[(tb + reg) * 256 + n0] = dacc0[reg] + b0;
            y[(tb + reg) * 256 + n1] = dacc1[reg] + b1;
        }
    }
}

extern "C" void kernel_launch(void* const* d_in, const int* in_sizes, int n_in,
                              void* d_out, int out_size, void* d_ws, size_t ws_size,
                              hipStream_t stream)
{
    const float* x    = (const float*)d_in[0];
    const int*   nidx = (const int*)  d_in[1];
    const float* nw   = (const float*)d_in[2];
    const float* rec  = (const float*)d_in[3];
    const float* A1   = (const float*)d_in[4];
    const float* A2   = (const float*)d_in[5];
    const float* B1   = (const float*)d_in[6];
    const float* B2   = (const float*)d_in[7];
    const float* Wd   = (const float*)d_in[8];
    const float* bd   = (const float*)d_in[9];
    float* y  = (float*)d_out;

    float* wr  = (float*)d_ws;                   // 8192*32 f32
    float* h   = wr + 8192 * 32;                 // 8192*64 f32
    u16* wrAh  = (u16*)(h + 8192 * 64);          // 262144 u16
    u16* wrAl  = wrAh + 262144;
    u16* b1h   = wrAl + 262144;                  // 65536 u16 each
    u16* b1l   = b1h + 65536;
    u16* b2h   = b1l + 65536;
    u16* b2l   = b2h + 65536;
    u16* wfh   = b2l + 65536;                    // 262144 u16 each
    u16* wfl   = wfh + 262144;

    k_route <<<128,  64,   0, stream>>>(nidx, nw, rec, wr, wrAh, wrAl);
    k_stageA<<<1024, 512,  0, stream>>>(x, wr, A1, A2, h);
    k_bsplit<<<64,   256,  0, stream>>>(B1, B2, b1h, b1l, b2h, b2l);
    k_wsplit<<<128,  256,  0, stream>>>(Wd, wfh, wfl);
    k_fusedB<<<512,  1024, 0, stream>>>(h, wrAh, wrAl, b1h, b1l, b2h, b2l, wfh, wfl, bd, y);
}

// Round 12
// 98.064 us; speedup vs baseline: 1.4129x; 1.0105x over previous
//
#include <hip/hip_runtime.h>
#include <math.h>

// B*S = 8192 tokens, K=8, N_BASIS=32, RANK=8, D_MODEL=256, D_HID=1024
// ws: wr f32 | h f32 | wrAh/wrAl | bf1h,bf1l,bf2h,bf2l | wfh,wfl  (~5.8 MB)
// stageB+down fused; P3 now runs on mfma_f32_32x32x16_bf16 (K=16 windows over r-pairs).

typedef unsigned short u16;
typedef __attribute__((ext_vector_type(8))) __bf16 bf16x8;
typedef __attribute__((ext_vector_type(4))) float f32x4;
typedef __attribute__((ext_vector_type(16))) float f32x16;
union ABCast { float4 f; bf16x8 v; };
union BFBits { __bf16 b; u16 u; };
union Pack8 { u16 u[8]; float4 f; };

__device__ __forceinline__ float gelu_exact(float v) {
    return 0.5f * v * (1.0f + erff(v * 0.70710678118654752440f));
}
__device__ __forceinline__ u16 f2bf_bits(float f) { BFBits c; c.b = (__bf16)f; return c.u; }
__device__ __forceinline__ float bfbits2f(u16 u) { BFBits c; c.u = u; return (float)c.b; }

// ---------------- K1: routing -> wr f32 + wr A-frags (bf16 h/l) ----------------
__global__ __launch_bounds__(64) void k_route(
    const int* __restrict__ nidx, const float* __restrict__ nw,
    const float* __restrict__ recipes, float* __restrict__ wr_out,
    u16* __restrict__ wrAh, u16* __restrict__ wrAl)
{
    const int t = blockIdx.x * 64 + threadIdx.x;
    float acc[32];
#pragma unroll
    for (int n = 0; n < 32; n++) acc[n] = 0.f;
#pragma unroll
    for (int k = 0; k < 8; k++) {
        const int   id = nidx[t * 8 + k];
        const float wk = nw[t * 8 + k];
        const float4* row = (const float4*)(recipes + id * 32);
        float v[32];
#pragma unroll
        for (int q = 0; q < 8; q++) {
            float4 f = row[q];
            v[q*4+0] = f.x; v[q*4+1] = f.y; v[q*4+2] = f.z; v[q*4+3] = f.w;
        }
        float m = v[0];
#pragma unroll
        for (int n = 1; n < 32; n++) m = fmaxf(m, v[n]);
        float s = 0.f;
#pragma unroll
        for (int n = 0; n < 32; n++) { float e = expf(v[n] - m); v[n] = e; s += e; }
        const float iv = wk / s;
#pragma unroll
        for (int n = 0; n < 32; n++) acc[n] += v[n] * iv;
    }
    float4* o = (float4*)(wr_out + t * 32);
#pragma unroll
    for (int q = 0; q < 8; q++)
        o[q] = make_float4(acc[q*4+0], acc[q*4+1], acc[q*4+2], acc[q*4+3]);

    const int tg16 = t >> 4, tl = t & 15;
#pragma unroll
    for (int c = 0; c < 4; c++) {
        Pack8 ph, pl;
#pragma unroll
        for (int e = 0; e < 8; e++) {
            const float v = acc[c*8 + e];
            const u16 hb = f2bf_bits(v);
            ph.u[e] = hb;
            pl.u[e] = f2bf_bits(v - bfbits2f(hb));
        }
        const int lane = c * 16 + tl;
        *(float4*)(wrAh + (tg16*64 + lane)*8) = ph.f;
        *(float4*)(wrAl + (tg16*64 + lane)*8) = pl.f;
    }
}

// ---------------- K2: stage A (unchanged) ----------------
__global__ __launch_bounds__(512) void k_stageA(
    const float* __restrict__ x, const float* __restrict__ wr,
    const float* __restrict__ A1, const float* __restrict__ A2,
    float* __restrict__ h_out)
{
    __shared__ float ca[8 * 1024];
    __shared__ float tl[8 * 1088];
    const int tid = threadIdx.x;
    const int t0  = blockIdx.x * 8;
    {
        const int e2 = tid * 2;
        float2 c[8];
#pragma unroll
        for (int tt = 0; tt < 8; tt++) c[tt] = make_float2(0.f, 0.f);
#pragma unroll 4
        for (int n = 0; n < 32; n++) {
            const float2 a = *(const float2*)(A1 + n * 1024 + e2);
#pragma unroll
            for (int tt = 0; tt < 8; tt++) {
                const float s = wr[(t0 + tt) * 32 + n];
                c[tt].x += s * a.x; c[tt].y += s * a.y;
            }
        }
#pragma unroll
        for (int tt = 0; tt < 8; tt++) *(float2*)(ca + tt * 1024 + e2) = c[tt];
    }
    __syncthreads();
    {
        const int t = tid >> 6, g = tid & 63, j = g >> 2, eh = g & 3;
        float xr[16];
#pragma unroll
        for (int i = 0; i < 16; i++) xr[i] = x[(t0 + t) * 256 + i * 16 + j];
        float tr[16];
#pragma unroll
        for (int q = 0; q < 16; q++) tr[q] = 0.f;
#pragma unroll
        for (int i = 0; i < 16; i++) {
            const float xv = xr[i];
#pragma unroll
            for (int q = 0; q < 4; q++) {
                const float4 cv = *(const float4*)(ca + t * 1024 + i * 64 + eh * 16 + q * 4);
                tr[q*4+0] += xv * cv.x; tr[q*4+1] += xv * cv.y;
                tr[q*4+2] += xv * cv.z; tr[q*4+3] += xv * cv.w;
            }
        }
#pragma unroll
        for (int q = 0; q < 4; q++)
            *(float4*)(tl + t * 1088 + j * 68 + eh * 16 + q * 4) =
                make_float4(tr[q*4+0], tr[q*4+1], tr[q*4+2], tr[q*4+3]);
    }
    __syncthreads();
    {
        const int e2 = tid * 2;
        float2 c[8];
#pragma unroll
        for (int tt = 0; tt < 8; tt++) c[tt] = make_float2(0.f, 0.f);
#pragma unroll 4
        for (int n = 0; n < 32; n++) {
            const float2 a = *(const float2*)(A2 + n * 1024 + e2);
#pragma unroll
            for (int tt = 0; tt < 8; tt++) {
                const float s = wr[(t0 + tt) * 32 + n];
                c[tt].x += s * a.x; c[tt].y += s * a.y;
            }
        }
#pragma unroll
        for (int tt = 0; tt < 8; tt++) *(float2*)(ca + tt * 1024 + e2) = c[tt];
    }
    __syncthreads();
    {
        const int t = tid >> 6, g = tid & 63, k = g >> 3, l = g & 7;
        float acc = 0.f;
#pragma unroll
        for (int j = 0; j < 16; j++) {
#pragma unroll
            for (int r = 0; r < 8; r++) {
                acc += tl[t * 1088 + j * 68 + r * 8 + k] *
                       ca[t * 1024 + r * 128 + j * 8 + l];
            }
        }
        h_out[(t0 + t) * 64 + g] = acc;
    }
}

// ---------------- K3a: basis banks -> bf16 h/l B-frags (unchanged) ----------------
__global__ __launch_bounds__(256) void k_bsplit(
    const float* __restrict__ B1, const float* __restrict__ B2,
    u16* __restrict__ o1h, u16* __restrict__ o1l,
    u16* __restrict__ o2h, u16* __restrict__ o2l)
{
    const int slot = blockIdx.x * 256 + threadIdx.x;
    const int bank = slot >> 13, r = (slot >> 10) & 7, g = (slot >> 6) & 15, l = slot & 63;
    const int c = l & 15, nb = 8 * (l >> 4);
    const int base = (bank == 0)
        ? ((g >> 1) * 256 + r * 32 + (g & 1) * 16 + c)
        : (r * 256 + (g >> 1) * 32 + (g & 1) * 16 + c);
    const float* S = (bank ? B2 : B1) + base + nb * 2048;
    Pack8 ph, pl;
#pragma unroll
    for (int e = 0; e < 8; e++) {
        const float v = S[e * 2048];
        const u16 hb = f2bf_bits(v);
        ph.u[e] = hb;
        pl.u[e] = f2bf_bits(v - bfbits2f(hb));
    }
    const int d = ((r * 16 + g) * 64 + l) * 8;
    *(float4*)((bank ? o2h : o1h) + d) = ph.f;
    *(float4*)((bank ? o2l : o1l) + d) = pl.f;
}

// ---------------- K3b: W -> bf16 h/l B-frags (unchanged) ----------------
__global__ __launch_bounds__(256) void k_wsplit(
    const float* __restrict__ W, u16* __restrict__ wfh, u16* __restrict__ wfl)
{
    const int slot = blockIdx.x * 256 + threadIdx.x;
    const int ng = slot >> 11, kc = (slot >> 6) & 31, l = slot & 63;
    const float* S = W + (kc * 32 + 8 * (l >> 4)) * 256 + ng * 16 + (l & 15);
    Pack8 ph, pl;
#pragma unroll
    for (int e = 0; e < 8; e++) {
        const float v = S[e * 256];
        const u16 hb = f2bf_bits(v);
        ph.u[e] = hb;
        pl.u[e] = f2bf_bits(v - bfbits2f(hb));
    }
    const int d = ((ng * 32 + kc) * 64 + l) * 8;
    *(float4*)(wfh + d) = ph.f;
    *(float4*)(wfl + d) = pl.f;
}

// ---------------- K4: fused stageB + down-proj (P3 via 32x32x16 MFMA windows) ----------
// Per r: BUILD cores (MFMA 16x16x32) -> cb1 f32 dbuf / cb2 bf16-h/l B-frag planes;
//        P2 (VALU) -> t2 bf16-h/l A-frag planes. Every 2 r's: one K=16 window of
//        mfma_f32_32x32x16_bf16 x3 (h/l split) accumulates out[32k][32l] per token-wave.
// Plane geometry: rows 24 u16 (48B: 16B-aligned b128 rows, ~4-way banks), token
// stride 1544 u16 (+8 slack: within-store tok-groups land 2-way/free).
// C/D 32x32 layout (HW-verified m74/m101): col=l&31, row=(reg&3)+8*(reg>>2)+4*(l>>5).
__global__ __launch_bounds__(1024, 2) void k_fusedB(
    const float* __restrict__ hin,
    const u16* __restrict__ wrAh, const u16* __restrict__ wrAl,
    const u16* __restrict__ bf1h, const u16* __restrict__ bf1l,
    const u16* __restrict__ bf2h, const u16* __restrict__ bf2l,
    const u16* __restrict__ wfh, const u16* __restrict__ wfl,
    const float* __restrict__ bias, float* __restrict__ y)
{
    __shared__ __align__(16) unsigned char smem[131584];
    float* cb1 = (float*)smem;                 // [2][16][256] f32  (32768 B)
    u16* t2p = (u16*)(smem + 32768);           // A-frag planes: [tok*1544][hl*768][k*24+kk]
    u16* c2p = (u16*)(smem + 82176);           // B-frag planes: [tok*1544][hl*768][lcol*24+kk]
    u16* gAh = (u16*)smem;                     // phase 2 (reuse, 64 KB)
    u16* gAl = gAh + 16384;

    const int tid = threadIdx.x;
    const int l   = tid & 63;
    const int w   = tid >> 6;                  // 0..15 = token
    const int tg  = blockIdx.x;
    const int t0  = tg * 16;
    const int jh  = l >> 5;                    // 0..1
    const int kP  = l & 31;                    // P2 k-row / window m-row / lcol

    // h for this wave's token: lane needs h[i*8 + jh*4+jj], i=0..7, jj=0..3 (L2 broadcast)
    float hreg[32];
#pragma unroll
    for (int i = 0; i < 8; i++)
#pragma unroll
        for (int jj = 0; jj < 4; jj++)
            hreg[i*4+jj] = hin[(t0 + w) * 64 + i * 8 + jh * 4 + jj];

    // wr A-frags
    ABCast cu;
    cu.f = *(const float4*)(wrAh + (tg * 64 + l) * 8); const bf16x8 wra_h = cu.v;
    cu.f = *(const float4*)(wrAl + (tg * 64 + l) * 8); const bf16x8 wra_l = cu.v;

    // BUILD assignment: waves 0-7 -> cb1 (f32 dbuf), 8-15 -> cb2 (carried, frag-stored)
    const bool isB2 = (w >= 8);
    const u16* bsrc_h = isB2 ? bf2h : bf1h;
    const u16* bsrc_l = isB2 ? bf2l : bf1l;
    const int g0 = (w & 7) * 2;

    f32x16 accw = {0.f,0.f,0.f,0.f,0.f,0.f,0.f,0.f,0.f,0.f,0.f,0.f,0.f,0.f,0.f,0.f};
    f32x4 ccA, ccB;                            // carried cb2 C-frags (waves>=8)

    float4 pbh0, pbl0, pbh1, pbl1;
#define LOADB(R) {                                                              \
    const int rb_ = (R) * 16;                                                   \
    pbh0 = *(const float4*)(bsrc_h + ((rb_ + g0 + 0)*64 + l)*8);                \
    pbl0 = *(const float4*)(bsrc_l + ((rb_ + g0 + 0)*64 + l)*8);                \
    pbh1 = *(const float4*)(bsrc_h + ((rb_ + g0 + 1)*64 + l)*8);                \
    pbl1 = *(const float4*)(bsrc_l + ((rb_ + g0 + 1)*64 + l)*8); }
#define BUILD(BSEL) {                                                           \
    ABCast ch_, cl_;                                                            \
    __builtin_amdgcn_s_setprio(1);                                              \
    ch_.f = pbh0; cl_.f = pbl0;                                                 \
    f32x4 t0_ = {0.f, 0.f, 0.f, 0.f};                                           \
    t0_ = __builtin_amdgcn_mfma_f32_16x16x32_bf16(wra_h, ch_.v, t0_, 0, 0, 0);  \
    t0_ = __builtin_amdgcn_mfma_f32_16x16x32_bf16(wra_h, cl_.v, t0_, 0, 0, 0);  \
    t0_ = __builtin_amdgcn_mfma_f32_16x16x32_bf16(wra_l, ch_.v, t0_, 0, 0, 0);  \
    ch_.f = pbh1; cl_.f = pbl1;                                                 \
    f32x4 t1_ = {0.f, 0.f, 0.f, 0.f};                                           \
    t1_ = __builtin_amdgcn_mfma_f32_16x16x32_bf16(wra_h, ch_.v, t1_, 0, 0, 0);  \
    t1_ = __builtin_amdgcn_mfma_f32_16x16x32_bf16(wra_h, cl_.v, t1_, 0, 0, 0);  \
    t1_ = __builtin_amdgcn_mfma_f32_16x16x32_bf16(wra_l, ch_.v, t1_, 0, 0, 0);  \
    __builtin_amdgcn_s_setprio(0);                                              \
    ccA = t0_; ccB = t1_;                                                       \
    if (w < 8) {                                                                \
        float* cdst = cb1 + (BSEL) * 4096;                                      \
        { const int gg = g0;                                                    \
          float* cd = cdst + (gg >> 1) * 32 + (gg & 1) * 16 + (l & 15);         \
          _Pragma("unroll")                                                     \
          for (int rg = 0; rg < 4; rg++) cd[(4*(l>>4)+rg)*256] = ccA[rg]; }     \
        { const int gg = g0 + 1;                                                \
          float* cd = cdst + (gg >> 1) * 32 + (gg & 1) * 16 + (l & 15);         \
          _Pragma("unroll")                                                     \
          for (int rg = 0; rg < 4; rg++) cd[(4*(l>>4)+rg)*256] = ccB[rg]; } } }
#define STORECB2(R) if (w >= 8) {                                               \
    _Pragma("unroll")                                                           \
    for (int gi = 0; gi < 2; gi++) {                                            \
        const int gg = g0 + gi, jj_ = gg >> 1;                                  \
        const int lc_ = (gg & 1) * 16 + (l & 15);                               \
        _Pragma("unroll")                                                       \
        for (int rg = 0; rg < 4; rg++) {                                        \
            const float vv = gi ? ccB[rg] : ccA[rg];                            \
            const u16 hb = f2bf_bits(vv);                                       \
            const u16 lb = f2bf_bits(vv - bfbits2f(hb));                        \
            const int tok = 4 * (l >> 4) + rg;                                  \
            const int idx = tok * 1544 + lc_ * 24 + 8 * ((R) & 1) + jj_;        \
            c2p[idx] = hb; c2p[idx + 768] = lb;                                 \
        } } }
#define WINDOW() {                                                              \
    ABCast ua, ub;                                                              \
    const int ab = w * 1544 + kP * 24 + 8 * jh;                                 \
    ua.f = *(const float4*)(t2p + ab);       const bf16x8 Ah = ua.v;            \
    ua.f = *(const float4*)(t2p + ab + 768); const bf16x8 Al = ua.v;            \
    ub.f = *(const float4*)(c2p + ab);       const bf16x8 Bh = ub.v;            \
    ub.f = *(const float4*)(c2p + ab + 768); const bf16x8 Bl = ub.v;            \
    accw = __builtin_amdgcn_mfma_f32_32x32x16_bf16(Ah, Bh, accw, 0, 0, 0);      \
    accw = __builtin_amdgcn_mfma_f32_32x32x16_bf16(Ah, Bl, accw, 0, 0, 0);      \
    accw = __builtin_amdgcn_mfma_f32_32x32x16_bf16(Al, Bh, accw, 0, 0, 0); }

    // prologue
    LOADB(0);
    BUILD(0);
    LOADB(1);
    __syncthreads();

#pragma unroll 1
    for (int r = 0; r < 8; r++) {
        if (r > 0 && (r & 1) == 0) {
            WINDOW();                // consume window (r/2 - 1): cols written r-2, r-1
            __syncthreads();         // protect planes before this iter's overwrites
        }
        STORECB2(r);                 // carried BUILD(r) C-frags -> B-frag planes
        if (r < 7) {
            BUILD((r + 1) & 1);      // cb1 -> dbuf; cb2 -> carried regs
            if (r < 6) LOADB(r + 2);
        }
        // ---- P2: t2[j][kP] = sum_i hreg[i][jj]*cb1[i*32+kP]; j = jh*4+jj ----
        {
            const float* c1b = cb1 + (r & 1) * 4096 + w * 256;
            float tv0 = 0.f, tv1 = 0.f, tv2 = 0.f, tv3 = 0.f;
#pragma unroll
            for (int i = 0; i < 8; i++) {
                const float cv = c1b[i * 32 + kP];
                tv0 += hreg[i*4+0] * cv; tv1 += hreg[i*4+1] * cv;
                tv2 += hreg[i*4+2] * cv; tv3 += hreg[i*4+3] * cv;
            }
            const u16 h0 = f2bf_bits(tv0), h1 = f2bf_bits(tv1),
                      h2 = f2bf_bits(tv2), h3 = f2bf_bits(tv3);
            const u16 q0 = f2bf_bits(tv0 - bfbits2f(h0)), q1 = f2bf_bits(tv1 - bfbits2f(h1)),
                      q2 = f2bf_bits(tv2 - bfbits2f(h2)), q3 = f2bf_bits(tv3 - bfbits2f(h3));
            const int tb = w * 1544 + kP * 24 + 8 * (r & 1) + jh * 4;
            *(ushort4*)(t2p + tb)       = make_ushort4(h0, h1, h2, h3);
            *(ushort4*)(t2p + tb + 768) = make_ushort4(q0, q1, q2, q3);
        }
        __syncthreads();
    }
    WINDOW();                        // final window (r=6,7)
    __syncthreads();

    // ---- epilogue: gelu + split -> gA frags (clobbers cb1/t2 regions: safe) ----
    {
#pragma unroll
        for (int rg = 0; rg < 16; rg++) {
            const int kk = (rg & 3) + 8 * (rg >> 2) + 4 * jh;   // C/D row = k index
            const float v = gelu_exact(accw[rg]);
            const u16 hb = f2bf_bits(v);
            const u16 lb = f2bf_bits(v - bfbits2f(hb));
            const int idx = (kk * 64 + (kP >> 3) * 16 + w) * 8 + (kP & 7);
            gAh[idx] = hb; gAl[idx] = lb;
        }
    }
    __syncthreads();

    // ---- down-proj: y[16][256] = g @ W + b ; waves 0-7, wave w owns n-groups {w, w+8} ----
    if (w < 8) {
        f32x4 dacc0 = {0.f, 0.f, 0.f, 0.f}, dacc1 = {0.f, 0.f, 0.f, 0.f};
        const int wb0 = w * 16384 + l * 8;
        const int wb1 = (w + 8) * 16384 + l * 8;
#pragma unroll 2
        for (int kc = 0; kc < 32; kc++) {
            cu.f = *(const float4*)(gAh + (kc * 64 + l) * 8); const bf16x8 ah = cu.v;
            cu.f = *(const float4*)(gAl + (kc * 64 + l) * 8); const bf16x8 al = cu.v;
            ABCast c0, c1, c2, c3;
            c0.f = *(const float4*)(wfh + wb0 + kc * 512); const bf16x8 bh0 = c0.v;
            c1.f = *(const float4*)(wfl + wb0 + kc * 512); const bf16x8 bl0 = c1.v;
            c2.f = *(const float4*)(wfh + wb1 + kc * 512); const bf16x8 bh1 = c2.v;
            c3.f = *(const float4*)(wfl + wb1 + kc * 512); const bf16x8 bl1 = c3.v;
            dacc0 = __builtin_amdgcn_mfma_f32_16x16x32_bf16(ah, bh0, dacc0, 0, 0, 0);
            dacc0 = __builtin_amdgcn_mfma_f32_16x16x32_bf16(ah, bl0, dacc0, 0, 0, 0);
            dacc0 = __builtin_amdgcn_mfma_f32_16x16x32_bf16(al, bh0, dacc0, 0, 0, 0);
            dacc1 = __builtin_amdgcn_mfma_f32_16x16x32_bf16(ah, bh1, dacc1, 0, 0, 0);
            dacc1 = __builtin_amdgcn_mfma_f32_16x16x32_bf16(ah, bl1, dacc1, 0, 0, 0);
            dacc1 = __builtin_amdgcn_mfma_f32_16x16x32_bf16(al, bh1, dacc1, 0, 0, 0);
        }
        const int n0 = w * 16 + (l & 15);
        const int n1 = (w + 8) * 16 + (l & 15);
        const float b0 = bias[n0], b1 = bias[n1];
        const int tb = t0 + 4 * (l >> 4);
#pragma unroll
        for (int rg = 0; rg < 4; rg++) {
            y[(tb + rg) * 256 + n0] = dacc0[rg] + b0;
            y[(tb + rg) * 256 + n1] = dacc1[rg] + b1;
        }
    }
#undef LOADB
#undef BUILD
#undef STORECB2
#undef WINDOW
}

extern "C" void kernel_launch(void* const* d_in, const int* in_sizes, int n_in,
                              void* d_out, int out_size, void* d_ws, size_t ws_size,
                              hipStream_t stream)
{
    const float* x    = (const float*)d_in[0];
    const int*   nidx = (const int*)  d_in[1];
    const float* nw   = (const float*)d_in[2];
    const float* rec  = (const float*)d_in[3];
    const float* A1   = (const float*)d_in[4];
    const float* A2   = (const float*)d_in[5];
    const float* B1   = (const float*)d_in[6];
    const float* B2   = (const float*)d_in[7];
    const float* Wd   = (const float*)d_in[8];
    const float* bd   = (const float*)d_in[9];
    float* y  = (float*)d_out;

    float* wr  = (float*)d_ws;                   // 8192*32 f32
    float* h   = wr + 8192 * 32;                 // 8192*64 f32
    u16* wrAh  = (u16*)(h + 8192 * 64);          // 262144 u16
    u16* wrAl  = wrAh + 262144;
    u16* b1h   = wrAl + 262144;                  // 65536 u16 each
    u16* b1l   = b1h + 65536;
    u16* b2h   = b1l + 65536;
    u16* b2l   = b2h + 65536;
    u16* wfh   = b2l + 65536;                    // 262144 u16 each
    u16* wfl   = wfh + 262144;

    k_route <<<128,  64,   0, stream>>>(nidx, nw, rec, wr, wrAh, wrAl);
    k_stageA<<<1024, 512,  0, stream>>>(x, wr, A1, A2, h);
    k_bsplit<<<64,   256,  0, stream>>>(B1, B2, b1h, b1l, b2h, b2l);
    k_wsplit<<<128,  256,  0, stream>>>(Wd, wfh, wfl);
    k_fusedB<<<512,  1024, 0, stream>>>(h, wrAh, wrAl, b1h, b1l, b2h, b2l, wfh, wfl, bd, y);
}